// Round 3
// baseline (327.933 us; speedup 1.0000x reference)
//
#include <hip/hip_runtime.h>

#define NROWS 8192   // N == M == 8192
#define DDIM  512
#define OUTN  8192

typedef int   i32x4 __attribute__((ext_vector_type(4)));
typedef int   i32x8 __attribute__((ext_vector_type(8)));
typedef float f32x4 __attribute__((ext_vector_type(4)));

__device__ __forceinline__ void gload_lds16(const void* g, void* l) {
    __builtin_amdgcn_global_load_lds(
        (const __attribute__((address_space(1))) void*)g,
        (__attribute__((address_space(3))) void*)l, 16, 0, 0);
}

// ---------------------------------------------------------------------------
// Prepass: fp32 -> fp8 e4m3 (OCP) + fp32 row sq-norms. One wave per row.
// ---------------------------------------------------------------------------
__global__ void __launch_bounds__(256)
rbf_prep(const float* __restrict__ x, const float* __restrict__ y,
         unsigned char* __restrict__ xb, unsigned char* __restrict__ yb,
         float* __restrict__ x2, float* __restrict__ y2) {
    int wave = (blockIdx.x * blockDim.x + threadIdx.x) >> 6;  // 0..16383
    int lane = threadIdx.x & 63;

    const float* src;
    unsigned char* dst;
    float* nrm;
    int row;
    if (wave < NROWS) { src = x; dst = xb; nrm = x2; row = wave; }
    else              { src = y; dst = yb; nrm = y2; row = wave - NROWS; }

    const float* p = src + (size_t)row * DDIM + lane * 8;
    float4 v0 = *(const float4*)(p);
    float4 v1 = *(const float4*)(p + 4);

    float s = v0.x * v0.x + v0.y * v0.y + v0.z * v0.z + v0.w * v0.w
            + v1.x * v1.x + v1.y * v1.y + v1.z * v1.z + v1.w * v1.w;

    int lo = __builtin_amdgcn_cvt_pk_fp8_f32(v0.x, v0.y, 0, false);
    lo     = __builtin_amdgcn_cvt_pk_fp8_f32(v0.z, v0.w, lo, true);
    int hi = __builtin_amdgcn_cvt_pk_fp8_f32(v1.x, v1.y, 0, false);
    hi     = __builtin_amdgcn_cvt_pk_fp8_f32(v1.z, v1.w, hi, true);
    *(int2*)(dst + (size_t)row * DDIM + lane * 8) = make_int2(lo, hi);

#pragma unroll
    for (int off = 32; off > 0; off >>= 1) s += __shfl_down(s, off, 64);
    if (lane == 0) nrm[row] = s;
}

// ---------------------------------------------------------------------------
// Fused GEMM + RBF epilogue, MX-fp8 (scale = 1.0).
// 128x128 block tile, BK=256 (2 K-iters -> 2 barrier pairs instead of 4),
// LDS 64 KB -> 2 blocks/CU co-resident so one block's staging drain overlaps
// the other's MFMA phase. 4 waves (2x2), each wave 4x4 of
// mfma_scale_f32_16x16x128_f8f6f4 per 128-k window (2 windows per iter).
// Swizzle: LDS chunk = global chunk ^ (row & 15) (256-B row stride would
// otherwise put all 16 fragment rows on the same 4 banks). LDS dest of
// global_load_lds stays base + lane*16 (HW requirement) — swizzle is applied
// on the global-address side.
// ---------------------------------------------------------------------------
__global__ void __launch_bounds__(256, 2)
rbf_gemm(const unsigned char* __restrict__ xb,
         const unsigned char* __restrict__ yb,
         const float* __restrict__ x2, const float* __restrict__ y2,
         const float* __restrict__ gamma, float* __restrict__ out) {
    __shared__ __attribute__((aligned(16))) unsigned char As[128 * 256];
    __shared__ __attribute__((aligned(16))) unsigned char Bs[128 * 256];

    const int tid  = threadIdx.x;
    const int lane = tid & 63;
    const int w    = tid >> 6;        // wave 0..3
    const int wm   = w & 1;           // wave row (0..1)
    const int wn   = w >> 1;          // wave col (0..1)

    const int bm = blockIdx.x & 63;
    const int bn = blockIdx.x >> 6;
    const int row0 = bm * 128;
    const int col0 = bn * 128;

    f32x4 acc[4][4] = {};

    // staging: each issue stages 4 rows x 256 B; lane L -> row L>>4, chunk L&15
    const int srl = lane >> 4;        // row within 4-row group
    const int slc = lane & 15;        // LDS chunk this lane fills

    for (int k0 = 0; k0 < DDIM; k0 += 256) {
#pragma unroll
        for (int i = 0; i < 8; ++i) {
            int rg  = w * 32 + i * 4;          // wave-uniform row group (4 rows)
            int row = rg + srl;
            int gc  = slc ^ (row & 15);        // global chunk -> this LDS slot
            gload_lds16(xb + (size_t)(row0 + row) * DDIM + k0 + gc * 16,
                        As + rg * 256);
            gload_lds16(yb + (size_t)(col0 + row) * DDIM + k0 + gc * 16,
                        Bs + rg * 256);
        }
        __syncthreads();

        const int fr = lane & 15;              // fragment row low bits (= row&15)
#pragma unroll
        for (int h = 0; h < 2; ++h) {          // two 128-k MFMA windows
            const int g2 = (lane >> 4) * 2 + h * 8;
            i32x8 af[4], bfr[4];
#pragma unroll
            for (int mi = 0; mi < 4; ++mi) {
                const unsigned char* base = As + (wm * 64 + mi * 16 + fr) * 256;
                i32x4 lo = *(const i32x4*)(base + ((g2    ) ^ fr) * 16);
                i32x4 hi = *(const i32x4*)(base + ((g2 + 1) ^ fr) * 16);
                af[mi] = __builtin_shufflevector(lo, hi, 0, 1, 2, 3, 4, 5, 6, 7);
            }
#pragma unroll
            for (int ni = 0; ni < 4; ++ni) {
                const unsigned char* base = Bs + (wn * 64 + ni * 16 + fr) * 256;
                i32x4 lo = *(const i32x4*)(base + ((g2    ) ^ fr) * 16);
                i32x4 hi = *(const i32x4*)(base + ((g2 + 1) ^ fr) * 16);
                bfr[ni] = __builtin_shufflevector(lo, hi, 0, 1, 2, 3, 4, 5, 6, 7);
            }
#pragma unroll
            for (int mi = 0; mi < 4; ++mi)
#pragma unroll
                for (int ni = 0; ni < 4; ++ni)
                    acc[mi][ni] = __builtin_amdgcn_mfma_scale_f32_16x16x128_f8f6f4(
                        af[mi], bfr[ni], acc[mi][ni],
                        0, 0,          // cbsz/blgp = fp8 e4m3
                        0, 0x7F,       // A scale = 1.0 (E8M0 127)
                        0, 0x7F);      // B scale = 1.0
        }
        __syncthreads();
    }

    // Epilogue: out[r][c] = exp(-g * (x2[r] + y2[c] - 2*xy))
    // C/D layout (16x16): col = lane&15, row = (lane>>4)*4 + reg
    // Non-temporal stores: output is write-once, keep it out of L2 so the
    // fp8 input tiles stay resident.
    const float g = gamma[0];
#pragma unroll
    for (int mi = 0; mi < 4; ++mi) {
        const int rbase = row0 + wm * 64 + mi * 16 + (lane >> 4) * 4;
        float xn[4];
#pragma unroll
        for (int r = 0; r < 4; ++r) xn[r] = x2[rbase + r];
#pragma unroll
        for (int ni = 0; ni < 4; ++ni) {
            const int col = col0 + wn * 64 + ni * 16 + (lane & 15);
            const float yn = y2[col];
            float* op = out + (size_t)rbase * OUTN + col;
#pragma unroll
            for (int r = 0; r < 4; ++r) {
                float s = xn[r] + yn - 2.0f * acc[mi][ni][r];
                __builtin_nontemporal_store(__expf(-g * s), op + (size_t)r * OUTN);
            }
        }
    }
}

extern "C" void kernel_launch(void* const* d_in, const int* in_sizes, int n_in,
                              void* d_out, int out_size, void* d_ws, size_t ws_size,
                              hipStream_t stream) {
    const float* x     = (const float*)d_in[0];
    const float* y     = (const float*)d_in[1];
    const float* gamma = (const float*)d_in[2];
    float* out = (float*)d_out;

    // workspace: xb (4 MB) | yb (4 MB) | x2 (32 KB) | y2 (32 KB)
    char* ws = (char*)d_ws;
    unsigned char* xb = (unsigned char*)ws;
    unsigned char* yb = (unsigned char*)(ws + (size_t)NROWS * DDIM);
    float* x2 = (float*)(ws + (size_t)NROWS * DDIM * 2);
    float* y2 = (float*)(ws + (size_t)NROWS * DDIM * 2 + NROWS * 4);

    rbf_prep<<<4096, 256, 0, stream>>>(x, y, xb, yb, x2, y2);
    rbf_gemm<<<4096, 256, 0, stream>>>(xb, yb, x2, y2, gamma, out);
}